// Round 1
// baseline (361.186 us; speedup 1.0000x reference)
//
#include <hip/hip_runtime.h>

typedef __bf16 bf16x8 __attribute__((ext_vector_type(8)));
typedef float f32x4 __attribute__((ext_vector_type(4)));

#define GLDS(g, l) __builtin_amdgcn_global_load_lds(                              \
    (const __attribute__((address_space(1))) void*)(g),                            \
    (__attribute__((address_space(3))) void*)(l), 16, 0, 0)

__device__ __forceinline__ unsigned short f2bf(float f) {
  unsigned int u = __builtin_bit_cast(unsigned int, f);
  u = (u + 0x7fffu + ((u >> 16) & 1u)) >> 16;
  return (unsigned short)u;
}
__device__ __forceinline__ float bf2f(unsigned short h) {
  unsigned int u = ((unsigned int)h) << 16;
  return __builtin_bit_cast(float, u);
}

// ---------------- f32 -> bf16 convert (vectorized) ----------------
__global__ __launch_bounds__(256) void cvt_f32_bf16(
    const float* __restrict__ in, unsigned short* __restrict__ out, int n4) {
  int i = blockIdx.x * 256 + threadIdx.x;
  if (i < n4) {
    float4 v = ((const float4*)in)[i];
    ushort4 o;
    o.x = f2bf(v.x); o.y = f2bf(v.y); o.z = f2bf(v.z); o.w = f2bf(v.w);
    ((ushort4*)out)[i] = o;
  }
}

// ---------------- GEMM: C[i,j] = sum_k A[i,k]*B[j,k] + bias[j] ----------------
// A: [M][K] bf16 row-major, B: [N][K] bf16 row-major (i.e. B^T input), C: [M][N] f32
// 128x128 tile, BK=64, 256 threads (4 waves 2x2), each wave 64x64 via 4x4 16x16x32 frags.
__global__ __launch_bounds__(256) void gemm_bt_bias(
    const unsigned short* __restrict__ A, const unsigned short* __restrict__ Bw,
    const float* __restrict__ bias, float* __restrict__ C,
    int M, int N, int K) {
  __shared__ unsigned short As[128 * 64];
  __shared__ unsigned short Bs[128 * 64];
  const int tid = threadIdx.x;
  const int lane = tid & 63;
  const int wid = tid >> 6;
  const int wm = wid >> 1, wn = wid & 1;
  const int bx = blockIdx.x, by = blockIdx.y;

  const int srow = lane >> 3;        // 0..7 within 8-row chunk
  const int scol = (lane & 7) * 8;   // element offset within row (16B)
  const size_t Kl = (size_t)K;

  f32x4 acc[4][4] = {};

  for (int k0 = 0; k0 < K; k0 += 64) {
#pragma unroll
    for (int q = 0; q < 4; ++q) {
      const int chunk = wid * 4 + q;                  // 0..15, 8 rows each
      const int r = chunk * 8 + srow;
      const unsigned short* ga = A + (size_t)(by * 128 + r) * Kl + k0 + scol;
      GLDS(ga, (char*)As + chunk * 1024);
      const unsigned short* gb = Bw + (size_t)(bx * 128 + r) * Kl + k0 + scol;
      GLDS(gb, (char*)Bs + chunk * 1024);
    }
    __syncthreads();
#pragma unroll
    for (int kk = 0; kk < 2; ++kk) {
      const int ko = kk * 32 + (lane >> 4) * 8;
      bf16x8 af[4], bfg[4];
#pragma unroll
      for (int mi = 0; mi < 4; ++mi)
        af[mi] = *(const bf16x8*)&As[(wm * 64 + mi * 16 + (lane & 15)) * 64 + ko];
#pragma unroll
      for (int nj = 0; nj < 4; ++nj)
        bfg[nj] = *(const bf16x8*)&Bs[(wn * 64 + nj * 16 + (lane & 15)) * 64 + ko];
#pragma unroll
      for (int mi = 0; mi < 4; ++mi)
#pragma unroll
        for (int nj = 0; nj < 4; ++nj)
          acc[mi][nj] = __builtin_amdgcn_mfma_f32_16x16x32_bf16(
              af[mi], bfg[nj], acc[mi][nj], 0, 0, 0);
    }
    __syncthreads();
  }

#pragma unroll
  for (int nj = 0; nj < 4; ++nj) {
    const int col = bx * 128 + wn * 64 + nj * 16 + (lane & 15);
    const float bv_ = bias[col];
#pragma unroll
    for (int mi = 0; mi < 4; ++mi) {
      const int row0 = by * 128 + wm * 64 + mi * 16 + ((lane >> 4) << 2);
#pragma unroll
      for (int r = 0; r < 4; ++r)
        C[(size_t)(row0 + r) * N + col] = acc[mi][nj][r] + bv_;
    }
  }
}

// ---------------- feature map + head-split reshape ----------------
// in: f32 [4096][2048] (= [b*2048+s][h*64+d]); out: bf16 [bh][2048][64]
// mode 0: plain (V). mode 1: elu+1 + sum-normalize (K). mode 2: *0.125 then as 1 (Q).
__global__ __launch_bounds__(256) void featmap(
    const float* __restrict__ in, unsigned short* __restrict__ out, int mode) {
  const int lane = threadIdx.x & 63;
  const int w = threadIdx.x >> 6;
  const int g = blockIdx.x * 4 + w;   // 0..131071 = row*32 + h
  const int bs = g >> 5;              // row (b*2048+s)
  const int h = g & 31;
  float x = in[(size_t)bs * 2048 + h * 64 + lane];
  if (mode == 2) x *= 0.125f;
  if (mode >= 1) {
    x = (x > 0.f) ? (x + 1.f) : __expf(x);
    float s = x;
#pragma unroll
    for (int off = 32; off; off >>= 1) s += __shfl_xor(s, off, 64);
    x = x / (s + 1e-4f);
  }
  const int b = bs >> 11, sx = bs & 2047;
  out[((size_t)((b << 5) + h) * 2048 + sx) * 64 + lane] = f2bf(x);
}

// ---------------- pass1: per-chunk stateT[d][e] = sum_t v[t,d]*k[t,e] ----------------
// grid (32 chunks, 64 bh), 256 thr. C=64.
__global__ __launch_bounds__(256) void chunk_state(
    const unsigned short* __restrict__ Kn, const unsigned short* __restrict__ Vn,
    unsigned short* __restrict__ stT) {
  __shared__ unsigned short Kt[64 * 72];
  __shared__ unsigned short Vt[64 * 72];
  const int c = blockIdx.x, bh = blockIdx.y;
  const int tid = threadIdx.x, lane = tid & 63, wid = tid >> 6;
  const size_t base = (size_t)bh * 2048 * 64 + (size_t)c * 64 * 64;
#pragma unroll
  for (int i = 0; i < 16; ++i) {
    const int ii = i * 256 + tid;       // = t*64 + d
    const int t = ii >> 6, d = ii & 63;
    Kt[d * 72 + t] = Kn[base + ii];
    Vt[d * 72 + t] = Vn[base + ii];
  }
  __syncthreads();
  f32x4 acc[4] = {};
#pragma unroll
  for (int ks = 0; ks < 2; ++ks) {
    const int ko = ks * 32 + (lane >> 4) * 8;
    bf16x8 a = *(const bf16x8*)&Vt[(wid * 16 + (lane & 15)) * 72 + ko];
#pragma unroll
    for (int ej = 0; ej < 4; ++ej) {
      bf16x8 bb = *(const bf16x8*)&Kt[(ej * 16 + (lane & 15)) * 72 + ko];
      acc[ej] = __builtin_amdgcn_mfma_f32_16x16x32_bf16(a, bb, acc[ej], 0, 0, 0);
    }
  }
  const size_t obase = ((size_t)bh * 32 + c) * 4096;
#pragma unroll
  for (int ej = 0; ej < 4; ++ej) {
    const int e = ej * 16 + (lane & 15);
    const int d0 = wid * 16 + ((lane >> 4) << 2);
#pragma unroll
    for (int r = 0; r < 4; ++r)
      stT[obase + (size_t)(d0 + r) * 64 + e] = f2bf(acc[ej][r]);
  }
}

// ---------------- pass2: exclusive prefix over chunks ----------------
__global__ __launch_bounds__(256) void prefix_state(
    const unsigned short* __restrict__ stT, unsigned short* __restrict__ cumT) {
  const int bh = blockIdx.x, tid = threadIdx.x;
#pragma unroll
  for (int j = 0; j < 16; ++j) {
    const int e = j * 256 + tid;        // 0..4095
    float run = 0.f;
    for (int c = 0; c < 32; ++c) {
      const size_t idx = ((size_t)bh * 32 + c) * 4096 + e;
      const float v = bf2f(stT[idx]);
      cumT[idx] = f2bf(run);
      run += v;
    }
  }
}

// ---------------- pass3: out = (tril(Q K^T) V + Q stateT) * 0.125 ----------------
__global__ __launch_bounds__(256) void attn_intra(
    const unsigned short* __restrict__ Qn, const unsigned short* __restrict__ Kn,
    const unsigned short* __restrict__ Vn, const unsigned short* __restrict__ cumT,
    unsigned short* __restrict__ aout) {
  __shared__ unsigned short Qs[64 * 72];
  __shared__ unsigned short Ks[64 * 72];
  __shared__ unsigned short Vt[64 * 72];
  __shared__ unsigned short St[64 * 72];
  __shared__ unsigned short Ps[64 * 72];
  const int c = blockIdx.x, bh = blockIdx.y;
  const int tid = threadIdx.x, lane = tid & 63, wid = tid >> 6;
  const size_t base = (size_t)bh * 2048 * 64 + (size_t)c * 64 * 64;
  const size_t sbase = ((size_t)bh * 32 + c) * 4096;
#pragma unroll
  for (int i = 0; i < 16; ++i) {
    const int ii = i * 256 + tid;
    const int t = ii >> 6, d = ii & 63;
    Qs[t * 72 + d] = Qn[base + ii];
    Ks[t * 72 + d] = Kn[base + ii];
    Vt[d * 72 + t] = Vn[base + ii];
    St[t * 72 + d] = cumT[sbase + ii];   // rows = d, cols = e
  }
  __syncthreads();
  // S = Q K^T  (wave wid owns s-rows [wid*16, +16))
  f32x4 sacc[4] = {};
#pragma unroll
  for (int ks = 0; ks < 2; ++ks) {
    const int ko = ks * 32 + (lane >> 4) * 8;
    bf16x8 a = *(const bf16x8*)&Qs[(wid * 16 + (lane & 15)) * 72 + ko];
#pragma unroll
    for (int tj = 0; tj < 4; ++tj) {
      bf16x8 bb = *(const bf16x8*)&Ks[(tj * 16 + (lane & 15)) * 72 + ko];
      sacc[tj] = __builtin_amdgcn_mfma_f32_16x16x32_bf16(a, bb, sacc[tj], 0, 0, 0);
    }
  }
  // tril mask, write P (bf16) to LDS
#pragma unroll
  for (int tj = 0; tj < 4; ++tj) {
    const int t = tj * 16 + (lane & 15);
    const int s0 = wid * 16 + ((lane >> 4) << 2);
#pragma unroll
    for (int r = 0; r < 4; ++r) {
      const float v = (t <= s0 + r) ? sacc[tj][r] : 0.f;
      Ps[(s0 + r) * 72 + t] = f2bf(v);
    }
  }
  __syncthreads();
  // out = P @ V + Q @ StT
  f32x4 oacc[4] = {};
#pragma unroll
  for (int ks = 0; ks < 2; ++ks) {
    const int ko = ks * 32 + (lane >> 4) * 8;
    bf16x8 a = *(const bf16x8*)&Ps[(wid * 16 + (lane & 15)) * 72 + ko];
    bf16x8 a2 = *(const bf16x8*)&Qs[(wid * 16 + (lane & 15)) * 72 + ko];
#pragma unroll
    for (int dj = 0; dj < 4; ++dj) {
      bf16x8 bv_ = *(const bf16x8*)&Vt[(dj * 16 + (lane & 15)) * 72 + ko];
      oacc[dj] = __builtin_amdgcn_mfma_f32_16x16x32_bf16(a, bv_, oacc[dj], 0, 0, 0);
      bf16x8 bs_ = *(const bf16x8*)&St[(dj * 16 + (lane & 15)) * 72 + ko];
      oacc[dj] = __builtin_amdgcn_mfma_f32_16x16x32_bf16(a2, bs_, oacc[dj], 0, 0, 0);
    }
  }
  const int b = bh >> 5, h = bh & 31;
#pragma unroll
  for (int dj = 0; dj < 4; ++dj) {
    const int d = dj * 16 + (lane & 15);
    const int s0 = wid * 16 + ((lane >> 4) << 2);
#pragma unroll
    for (int r = 0; r < 4; ++r) {
      const size_t row = (size_t)(b * 2048 + c * 64 + s0 + r);
      aout[row * 2048 + h * 64 + d] = f2bf(0.125f * oacc[dj][r]);
    }
  }
}

extern "C" void kernel_launch(void* const* d_in, const int* in_sizes, int n_in,
                              void* d_out, int out_size, void* d_ws, size_t ws_size,
                              hipStream_t stream) {
  const float* hs = (const float*)d_in[0];
  // d_in[1] = attention_mask (tril, implemented analytically)
  const float* wq = (const float*)d_in[2];
  const float* bq = (const float*)d_in[3];
  const float* wk = (const float*)d_in[4];
  const float* bk = (const float*)d_in[5];
  const float* wv = (const float*)d_in[6];
  const float* bv = (const float*)d_in[7];
  const float* wo = (const float*)d_in[8];
  const float* bo = (const float*)d_in[9];
  float* out = (float*)d_out;
  char* ws = (char*)d_ws;

  // workspace layout (bytes)
  unsigned short* hs_bf = (unsigned short*)(ws);                    // 16 MiB
  unsigned short* wq_bf = (unsigned short*)(ws + 16777216);         // 8 MiB each
  unsigned short* wk_bf = wq_bf + 4194304;
  unsigned short* wv_bf = wk_bf + 4194304;
  unsigned short* wo_bf = wv_bf + 4194304;
  float* tmp           = (float*)(ws + 50331648);                   // 32 MiB
  unsigned short* Qn   = (unsigned short*)(ws + 83886080);          // 16 MiB
  unsigned short* Kn   = (unsigned short*)(ws + 100663296);
  unsigned short* Vn   = (unsigned short*)(ws + 117440512);
  unsigned short* stT  = (unsigned short*)(ws + 134217728);
  unsigned short* cumT = (unsigned short*)(ws + 150994944);
  unsigned short* aout = (unsigned short*)(ws + 167772160);         // ends 184 MiB

  // 1. converts
  cvt_f32_bf16<<<8192, 256, 0, stream>>>(hs, hs_bf, 2097152);
  cvt_f32_bf16<<<4096, 256, 0, stream>>>(wq, wq_bf, 1048576);
  cvt_f32_bf16<<<4096, 256, 0, stream>>>(wk, wk_bf, 1048576);
  cvt_f32_bf16<<<4096, 256, 0, stream>>>(wv, wv_bf, 1048576);
  cvt_f32_bf16<<<4096, 256, 0, stream>>>(wo, wo_bf, 1048576);

  const dim3 ggrid(16, 32);  // N/128, M/128
  // 2. Q
  gemm_bt_bias<<<ggrid, 256, 0, stream>>>(hs_bf, wq_bf, bq, tmp, 4096, 2048, 2048);
  featmap<<<32768, 256, 0, stream>>>(tmp, Qn, 2);
  // K
  gemm_bt_bias<<<ggrid, 256, 0, stream>>>(hs_bf, wk_bf, bk, tmp, 4096, 2048, 2048);
  featmap<<<32768, 256, 0, stream>>>(tmp, Kn, 1);
  // V
  gemm_bt_bias<<<ggrid, 256, 0, stream>>>(hs_bf, wv_bf, bv, tmp, 4096, 2048, 2048);
  featmap<<<32768, 256, 0, stream>>>(tmp, Vn, 0);

  // 3. linear-attention chunked
  chunk_state<<<dim3(32, 64), 256, 0, stream>>>(Kn, Vn, stT);
  prefix_state<<<64, 256, 0, stream>>>(stT, cumT);
  attn_intra<<<dim3(32, 64), 256, 0, stream>>>(Qn, Kn, Vn, cumT, aout);

  // 4. output projection
  gemm_bt_bias<<<ggrid, 256, 0, stream>>>(aout, wo_bf, bo, out, 4096, 2048, 2048);
}

// Round 2
// 218.281 us; speedup vs baseline: 1.6547x; 1.6547x over previous
//
#include <hip/hip_runtime.h>

typedef __bf16 bf16x8 __attribute__((ext_vector_type(8)));
typedef float f32x4 __attribute__((ext_vector_type(4)));

#define GLDS(g, l) __builtin_amdgcn_global_load_lds(                              \
    (const __attribute__((address_space(1))) void*)(g),                            \
    (__attribute__((address_space(3))) void*)(l), 16, 0, 0)

__device__ __forceinline__ unsigned short f2bf(float f) {
  unsigned int u = __builtin_bit_cast(unsigned int, f);
  u = (u + 0x7fffu + ((u >> 16) & 1u)) >> 16;
  return (unsigned short)u;
}
__device__ __forceinline__ float bf2f(unsigned short h) {
  unsigned int u = ((unsigned int)h) << 16;
  return __builtin_bit_cast(float, u);
}

// ---------------- f32 -> bf16 convert (vectorized) ----------------
__global__ __launch_bounds__(256) void cvt_f32_bf16(
    const float* __restrict__ in, unsigned short* __restrict__ out, int n4) {
  int i = blockIdx.x * 256 + threadIdx.x;
  if (i < n4) {
    float4 v = ((const float4*)in)[i];
    ushort4 o;
    o.x = f2bf(v.x); o.y = f2bf(v.y); o.z = f2bf(v.z); o.w = f2bf(v.w);
    ((ushort4*)out)[i] = o;
  }
}

// ---------------- phase-split GEMM, BM=128 BN=256 BK=64, 3-buf LDS ----------------
// C[i,j] = sum_k A[i,k]*B[j,k]; A [4096][2048] bf16, B [NB][2048] bf16 (B^T input).
// MODE 0: f32 out = acc + b0[col] -> (float*)o0, N_out=2048.
// MODE 1: QKV featmap epilogue -> bf16 [bh][2048][64] into o0/o1/o2 (Q/K/V).
// 512 thr = 8 waves (2M x 4N), per-wave 64x64 (4x4 16x16x32 frags).
template<int MODE, int NB, int CX, int CY>
__global__ __launch_bounds__(512, 2) void gemm128(
    const unsigned short* __restrict__ A, const unsigned short* __restrict__ Bw,
    const float* __restrict__ b0, const float* __restrict__ b1, const float* __restrict__ b2,
    void* __restrict__ o0, void* __restrict__ o1, void* __restrict__ o2) {
  constexpr int K = 2048, NT = 32;
  __shared__ unsigned short lds[73728];  // A: 3 x 16KB, B: 3 x 32KB = 144 KB
  const int tid = threadIdx.x, lane = tid & 63, wid = tid >> 6;
  const int wm = wid >> 2, wn = wid & 3;

  // XCD-aware bijective swizzle + chunked (CX x CY) tile mapping
  constexpr int NWG = (NB / 256) * 32;
  constexpr int CPX = NWG >> 3;
  constexpr int CCOLS = (NB / 256) / CX;
  const int g0 = blockIdx.x;
  const int wg = (g0 & 7) * CPX + (g0 >> 3);
  const int l = wg % (CX * CY);
  const int chunk = wg / (CX * CY);
  const int bx = (chunk % CCOLS) * CX + l / CY;   // N-tile (256 wide)
  const int by = (chunk / CCOLS) * CY + l % CY;   // M-tile (128 tall)

  // stage source pointers (pre-swizzled global col)
  const int rloc = wid * 8 + (lane >> 3);                 // row within 64-row call
  const size_t gcoff = (size_t)(((lane & 7) ^ (lane >> 3)) << 3);
  const unsigned short* gA[2];
  const unsigned short* gB[4];
#pragma unroll
  for (int c = 0; c < 2; ++c) gA[c] = A + (size_t)(by * 128 + c * 64 + rloc) * K + gcoff;
#pragma unroll
  for (int c = 0; c < 4; ++c) gB[c] = Bw + (size_t)(bx * 256 + c * 64 + rloc) * K + gcoff;

  // ds_read offsets (swizzled), in ushorts
  int aoff[4][2], boff[4][2];
#pragma unroll
  for (int m = 0; m < 4; ++m)
#pragma unroll
    for (int kk = 0; kk < 2; ++kk) {
      aoff[m][kk] = (wm * 64 + m * 16 + (lane & 15)) * 64 +
                    ((((kk << 2) + (lane >> 4)) ^ (lane & 7)) << 3);
      boff[m][kk] = (wn * 64 + m * 16 + (lane & 15)) * 64 +
                    ((((kk << 2) + (lane >> 4)) ^ (lane & 7)) << 3);
    }

  f32x4 acc[4][4] = {};

#define AB(b) ((b) * 8192)
#define BB(b) (24576 + (b) * 16384)
#define STAGE_A(c, b) GLDS(gA[c], lds + AB(b) + (c) * 4096 + wid * 512)
#define STAGE_B(c, b) GLDS(gB[c], lds + BB(b) + (c) * 4096 + wid * 512)

  // prologue: stage t=0 -> buf0, t=1 -> buf1 (12 calls in flight)
  STAGE_A(0, 0); STAGE_A(1, 0); STAGE_B(0, 0); STAGE_B(1, 0); STAGE_B(2, 0); STAGE_B(3, 0);
#pragma unroll
  for (int c = 0; c < 2; ++c) gA[c] += 64;
#pragma unroll
  for (int c = 0; c < 4; ++c) gB[c] += 64;
  STAGE_A(0, 1); STAGE_A(1, 1); STAGE_B(0, 1); STAGE_B(1, 1); STAGE_B(2, 1); STAGE_B(3, 1);
#pragma unroll
  for (int c = 0; c < 2; ++c) gA[c] += 64;
#pragma unroll
  for (int c = 0; c < 4; ++c) gB[c] += 64;
  asm volatile("s_waitcnt vmcnt(6)" ::: "memory");   // t=0 landed, t=1 in flight
  __builtin_amdgcn_s_barrier();

  for (int t = 0; t < NT; ++t) {
    const int b = t % 3;
    const int sb = (t + 2) % 3;
    const bool doStage = (t + 2 < NT);

    // ---- phase 0 (kk=0): stage 4 halves of t+2, read, mfma ----
    if (doStage) { STAGE_A(0, sb); STAGE_A(1, sb); STAGE_B(0, sb); STAGE_B(1, sb); }
    bf16x8 af[4], bfr[4];
#pragma unroll
    for (int m = 0; m < 4; ++m) af[m] = *(const bf16x8*)&lds[AB(b) + aoff[m][0]];
#pragma unroll
    for (int n = 0; n < 4; ++n) bfr[n] = *(const bf16x8*)&lds[BB(b) + boff[n][0]];
    __builtin_amdgcn_s_barrier();
    __builtin_amdgcn_s_setprio(1);
#pragma unroll
    for (int m = 0; m < 4; ++m)
#pragma unroll
      for (int n = 0; n < 4; ++n)
        acc[m][n] = __builtin_amdgcn_mfma_f32_16x16x32_bf16(af[m], bfr[n], acc[m][n], 0, 0, 0);
    __builtin_amdgcn_s_setprio(0);
    __builtin_amdgcn_s_barrier();

    // ---- phase 1 (kk=1): stage last 2 halves, read, mfma ----
    if (doStage) { STAGE_B(2, sb); STAGE_B(3, sb); }
#pragma unroll
    for (int c = 0; c < 2; ++c) gA[c] += 64;
#pragma unroll
    for (int c = 0; c < 4; ++c) gB[c] += 64;
#pragma unroll
    for (int m = 0; m < 4; ++m) af[m] = *(const bf16x8*)&lds[AB(b) + aoff[m][1]];
#pragma unroll
    for (int n = 0; n < 4; ++n) bfr[n] = *(const bf16x8*)&lds[BB(b) + boff[n][1]];
    __builtin_amdgcn_s_barrier();
    __builtin_amdgcn_s_setprio(1);
#pragma unroll
    for (int m = 0; m < 4; ++m)
#pragma unroll
      for (int n = 0; n < 4; ++n)
        acc[m][n] = __builtin_amdgcn_mfma_f32_16x16x32_bf16(af[m], bfr[n], acc[m][n], 0, 0, 0);
    __builtin_amdgcn_s_setprio(0);
    // counted boundary wait BEFORE the barrier so all waves' stages are resolved
    if (t < NT - 1) {
      if (doStage) asm volatile("s_waitcnt vmcnt(6)" ::: "memory");
      else         asm volatile("s_waitcnt vmcnt(0)" ::: "memory");
    }
    __builtin_amdgcn_s_barrier();
  }

  // ---------------- epilogue ----------------
  if constexpr (MODE == 0) {
    float* C = (float*)o0;
#pragma unroll
    for (int n = 0; n < 4; ++n) {
      const int col = bx * 256 + wn * 64 + n * 16 + (lane & 15);
      const float bv_ = b0[col];
#pragma unroll
      for (int m = 0; m < 4; ++m) {
        const int row0 = by * 128 + wm * 64 + m * 16 + ((lane >> 4) << 2);
#pragma unroll
        for (int r = 0; r < 4; ++r)
          C[(size_t)(row0 + r) * 2048 + col] = acc[m][n][r] + bv_;
      }
    }
  } else {
    const int head = bx * 4 + wn;        // 0..95
    const int type = head >> 5;          // 0 Q, 1 K, 2 V
    const int h = head & 31;
    const float* bias = (type == 0) ? b0 : (type == 1) ? b1 : b2;
    unsigned short* dst = (unsigned short*)((type == 0) ? o0 : (type == 1) ? o1 : o2);
    float bvals[4];
#pragma unroll
    for (int n = 0; n < 4; ++n) bvals[n] = bias[h * 64 + n * 16 + (lane & 15)];
#pragma unroll
    for (int m = 0; m < 4; ++m) {
#pragma unroll
      for (int r = 0; r < 4; ++r) {
        const int row = by * 128 + wm * 64 + m * 16 + ((lane >> 4) << 2) + r;
        const int bb = row >> 11, s = row & 2047;
        float e[4];
        float loc = 0.f;
#pragma unroll
        for (int n = 0; n < 4; ++n) {
          float v = acc[m][n][r] + bvals[n];
          if (type == 0) v *= 0.125f;
          if (type < 2) v = (v > 0.f) ? (v + 1.f) : __expf(v);
          e[n] = v; loc += v;
        }
        if (type < 2) {
#pragma unroll
          for (int off = 1; off < 16; off <<= 1) loc += __shfl_xor(loc, off, 64);
          const float inv = 1.f / (loc + 1e-4f);
#pragma unroll
          for (int n = 0; n < 4; ++n) e[n] *= inv;
        }
        const size_t base = ((size_t)((bb << 5) + h) * 2048 + s) * 64;
#pragma unroll
        for (int n = 0; n < 4; ++n) dst[base + n * 16 + (lane & 15)] = f2bf(e[n]);
      }
    }
  }
#undef AB
#undef BB
#undef STAGE_A
#undef STAGE_B
}

// ---------------- pass1: per-chunk stateT[d][e] = sum_t v[t,d]*k[t,e] ----------------
__global__ __launch_bounds__(256) void chunk_state(
    const unsigned short* __restrict__ Kn, const unsigned short* __restrict__ Vn,
    unsigned short* __restrict__ stT) {
  __shared__ unsigned short Kt[64 * 72];
  __shared__ unsigned short Vt[64 * 72];
  const int c = blockIdx.x, bh = blockIdx.y;
  const int tid = threadIdx.x, lane = tid & 63, wid = tid >> 6;
  const size_t base = (size_t)bh * 2048 * 64 + (size_t)c * 64 * 64;
#pragma unroll
  for (int i = 0; i < 16; ++i) {
    const int ii = i * 256 + tid;       // = t*64 + d
    const int t = ii >> 6, d = ii & 63;
    Kt[d * 72 + t] = Kn[base + ii];
    Vt[d * 72 + t] = Vn[base + ii];
  }
  __syncthreads();
  f32x4 acc[4] = {};
#pragma unroll
  for (int ks = 0; ks < 2; ++ks) {
    const int ko = ks * 32 + (lane >> 4) * 8;
    bf16x8 a = *(const bf16x8*)&Vt[(wid * 16 + (lane & 15)) * 72 + ko];
#pragma unroll
    for (int ej = 0; ej < 4; ++ej) {
      bf16x8 bb = *(const bf16x8*)&Kt[(ej * 16 + (lane & 15)) * 72 + ko];
      acc[ej] = __builtin_amdgcn_mfma_f32_16x16x32_bf16(a, bb, acc[ej], 0, 0, 0);
    }
  }
  const size_t obase = ((size_t)bh * 32 + c) * 4096;
#pragma unroll
  for (int ej = 0; ej < 4; ++ej) {
    const int e = ej * 16 + (lane & 15);
    const int d0 = wid * 16 + ((lane >> 4) << 2);
#pragma unroll
    for (int r = 0; r < 4; ++r)
      stT[obase + (size_t)(d0 + r) * 64 + e] = f2bf(acc[ej][r]);
  }
}

// ---------------- pass2: exclusive prefix over chunks (1 thread per (bh,e)) ----------------
__global__ __launch_bounds__(256) void prefix_state(
    const unsigned short* __restrict__ stT, unsigned short* __restrict__ cumT) {
  const int g = blockIdx.x * 256 + threadIdx.x;  // 0..262143
  const int bh = g >> 12, e = g & 4095;
  float run = 0.f;
  for (int c = 0; c < 32; ++c) {
    const size_t idx = (((size_t)bh * 32 + c) << 12) + e;
    const float v = bf2f(stT[idx]);
    cumT[idx] = f2bf(run);
    run += v;
  }
}

// ---------------- pass3: out = (tril(Q K^T) V + Q stateT) * 0.125 ----------------
__global__ __launch_bounds__(256) void attn_intra(
    const unsigned short* __restrict__ Qn, const unsigned short* __restrict__ Kn,
    const unsigned short* __restrict__ Vn, const unsigned short* __restrict__ cumT,
    unsigned short* __restrict__ aout) {
  __shared__ unsigned short Qs[64 * 72];
  __shared__ unsigned short Ks[64 * 72];
  __shared__ unsigned short Vt[64 * 72];
  __shared__ unsigned short St[64 * 72];
  __shared__ unsigned short Ps[64 * 72];
  const int c = blockIdx.x, bh = blockIdx.y;
  const int tid = threadIdx.x, lane = tid & 63, wid = tid >> 6;
  const size_t base = (size_t)bh * 2048 * 64 + (size_t)c * 64 * 64;
  const size_t sbase = ((size_t)bh * 32 + c) * 4096;
#pragma unroll
  for (int i = 0; i < 16; ++i) {
    const int ii = i * 256 + tid;
    const int t = ii >> 6, d = ii & 63;
    Qs[t * 72 + d] = Qn[base + ii];
    Ks[t * 72 + d] = Kn[base + ii];
    Vt[d * 72 + t] = Vn[base + ii];
    St[t * 72 + d] = cumT[sbase + ii];
  }
  __syncthreads();
  f32x4 sacc[4] = {};
#pragma unroll
  for (int ks = 0; ks < 2; ++ks) {
    const int ko = ks * 32 + (lane >> 4) * 8;
    bf16x8 a = *(const bf16x8*)&Qs[(wid * 16 + (lane & 15)) * 72 + ko];
#pragma unroll
    for (int tj = 0; tj < 4; ++tj) {
      bf16x8 bb = *(const bf16x8*)&Ks[(tj * 16 + (lane & 15)) * 72 + ko];
      sacc[tj] = __builtin_amdgcn_mfma_f32_16x16x32_bf16(a, bb, sacc[tj], 0, 0, 0);
    }
  }
#pragma unroll
  for (int tj = 0; tj < 4; ++tj) {
    const int t = tj * 16 + (lane & 15);
    const int s0 = wid * 16 + ((lane >> 4) << 2);
#pragma unroll
    for (int r = 0; r < 4; ++r) {
      const float v = (t <= s0 + r) ? sacc[tj][r] : 0.f;
      Ps[(s0 + r) * 72 + t] = f2bf(v);
    }
  }
  __syncthreads();
  f32x4 oacc[4] = {};
#pragma unroll
  for (int ks = 0; ks < 2; ++ks) {
    const int ko = ks * 32 + (lane >> 4) * 8;
    bf16x8 a = *(const bf16x8*)&Ps[(wid * 16 + (lane & 15)) * 72 + ko];
    bf16x8 a2 = *(const bf16x8*)&Qs[(wid * 16 + (lane & 15)) * 72 + ko];
#pragma unroll
    for (int dj = 0; dj < 4; ++dj) {
      bf16x8 bv_ = *(const bf16x8*)&Vt[(dj * 16 + (lane & 15)) * 72 + ko];
      oacc[dj] = __builtin_amdgcn_mfma_f32_16x16x32_bf16(a, bv_, oacc[dj], 0, 0, 0);
      bf16x8 bs_ = *(const bf16x8*)&St[(dj * 16 + (lane & 15)) * 72 + ko];
      oacc[dj] = __builtin_amdgcn_mfma_f32_16x16x32_bf16(a2, bs_, oacc[dj], 0, 0, 0);
    }
  }
  const int b = bh >> 5, h = bh & 31;
#pragma unroll
  for (int dj = 0; dj < 4; ++dj) {
    const int d = dj * 16 + (lane & 15);
    const int s0 = wid * 16 + ((lane >> 4) << 2);
#pragma unroll
    for (int r = 0; r < 4; ++r) {
      const size_t row = (size_t)(b * 2048 + c * 64 + s0 + r);
      aout[row * 2048 + h * 64 + d] = f2bf(0.125f * oacc[dj][r]);
    }
  }
}

extern "C" void kernel_launch(void* const* d_in, const int* in_sizes, int n_in,
                              void* d_out, int out_size, void* d_ws, size_t ws_size,
                              hipStream_t stream) {
  const float* hs = (const float*)d_in[0];
  const float* wq = (const float*)d_in[2];
  const float* bq = (const float*)d_in[3];
  const float* wk = (const float*)d_in[4];
  const float* bk = (const float*)d_in[5];
  const float* wv = (const float*)d_in[6];
  const float* bv = (const float*)d_in[7];
  const float* wo = (const float*)d_in[8];
  const float* bo = (const float*)d_in[9];
  float* out = (float*)d_out;
  char* ws = (char*)d_ws;

  // workspace layout (bytes)
  unsigned short* hs_bf   = (unsigned short*)(ws);               // 16 MiB
  unsigned short* wqkv_bf = (unsigned short*)(ws + 16777216);    // 24 MiB [wq|wk|wv]
  unsigned short* wo_bf   = (unsigned short*)(ws + 41943040);    // 8 MiB
  unsigned short* Qn      = (unsigned short*)(ws + 50331648);    // 16 MiB each
  unsigned short* Kn      = (unsigned short*)(ws + 67108864);
  unsigned short* Vn      = (unsigned short*)(ws + 83886080);
  unsigned short* stT     = (unsigned short*)(ws + 100663296);
  unsigned short* cumT    = (unsigned short*)(ws + 117440512);
  unsigned short* aout    = (unsigned short*)(ws + 134217728);   // ends 144 MiB

  // converts
  cvt_f32_bf16<<<8192, 256, 0, stream>>>(hs, hs_bf, 2097152);
  cvt_f32_bf16<<<4096, 256, 0, stream>>>(wq, wqkv_bf, 1048576);
  cvt_f32_bf16<<<4096, 256, 0, stream>>>(wk, wqkv_bf + 4194304, 1048576);
  cvt_f32_bf16<<<4096, 256, 0, stream>>>(wv, wqkv_bf + 8388608, 1048576);
  cvt_f32_bf16<<<4096, 256, 0, stream>>>(wo, wo_bf, 1048576);

  // fused QKV projection + feature map (N=6144, grid 768)
  gemm128<1, 6144, 6, 16><<<768, 512, 0, stream>>>(
      hs_bf, wqkv_bf, bq, bk, bv, Qn, Kn, Vn);

  // linear-attention chunked
  chunk_state<<<dim3(32, 64), 256, 0, stream>>>(Kn, Vn, stT);
  prefix_state<<<1024, 256, 0, stream>>>(stT, cumT);
  attn_intra<<<dim3(32, 64), 256, 0, stream>>>(Qn, Kn, Vn, cumT, aout);

  // output projection (N=2048, grid 256)
  gemm128<0, 2048, 2, 16><<<256, 512, 0, stream>>>(
      aout, wo_bf, bo, nullptr, nullptr, out, nullptr, nullptr);
}